// Round 1
// baseline (744.809 us; speedup 1.0000x reference)
//
#include <hip/hip_runtime.h>
#include <math.h>

// ---------------------------------------------------------------------------
// FraudDetectionGCN: 3x GCNConv(relu) + FC + log_softmax, fp32 throughout.
// Strategy: build dst-CSR per call (no float atomics), aggregation = gather
// with one wave per node (lane == feature, H=64 == wave width).
// norm factorization: out[n] = dinv[n]*(sum_{s->n} g[s] + g[n]) + b,
// where g = dinv[:,None] * (h @ W).
// ---------------------------------------------------------------------------

static inline size_t alignup(size_t x){ return (x + 511) & ~size_t(511); }

__global__ void zero_int_kernel(int* __restrict__ p, int n){
  int i = blockIdx.x*256 + threadIdx.x;
  if(i<n) p[i] = 0;
}

__global__ void count_deg_kernel(const int* __restrict__ dst, int* __restrict__ degi, int E){
  int e = blockIdx.x*256 + threadIdx.x;
  if(e<E) atomicAdd(&degi[dst[e]], 1);
}

__global__ void dinv_kernel(const int* __restrict__ degi, float* __restrict__ dinv, int N){
  int i = blockIdx.x*256 + threadIdx.x;
  if(i<N) dinv[i] = rsqrtf((float)(degi[i] + 1));   // +1: self loop; deg>0 always
}

// Block scans 1024 elements (4/thread * 256 threads). Exclusive scan within
// block -> part[], block total -> bsum[blockIdx].
__global__ void scan_block_kernel(const int* __restrict__ cnt, int* __restrict__ part,
                                  int* __restrict__ bsum, int N){
  __shared__ int sh[256];
  int t = threadIdx.x;
  int base = blockIdx.x*1024 + t*4;
  int v0 = (base+0<N)?cnt[base+0]:0;
  int v1 = (base+1<N)?cnt[base+1]:0;
  int v2 = (base+2<N)?cnt[base+2]:0;
  int v3 = (base+3<N)?cnt[base+3]:0;
  int tsum = v0+v1+v2+v3;
  sh[t] = tsum; __syncthreads();
  for(int off=1; off<256; off<<=1){
    int x = (t>=off)? sh[t-off] : 0;
    __syncthreads();
    sh[t] += x;
    __syncthreads();
  }
  int run = sh[t] - tsum;           // exclusive prefix of this thread
  if(t==255) bsum[blockIdx.x] = sh[255];
  if(base+0<N){ part[base+0]=run; run+=v0; }
  if(base+1<N){ part[base+1]=run; run+=v1; }
  if(base+2<N){ part[base+2]=run; run+=v2; }
  if(base+3<N){ part[base+3]=run; }
}

// Single block: exclusive-scan bsum[0..nb) in place (nb <= 256).
__global__ void scan_bsum_kernel(int* __restrict__ bsum, int nb){
  __shared__ int sh[256];
  int t = threadIdx.x;
  int v = (t<nb)? bsum[t] : 0;
  sh[t] = v; __syncthreads();
  for(int off=1; off<256; off<<=1){
    int x = (t>=off)? sh[t-off] : 0;
    __syncthreads();
    sh[t] += x;
    __syncthreads();
  }
  if(t<nb) bsum[t] = sh[t] - v;
}

__global__ void finalize_kernel(const int* __restrict__ part, const int* __restrict__ bsum,
                                int* __restrict__ row_ptr, int* __restrict__ fill, int N, int E){
  int i = blockIdx.x*256 + threadIdx.x;
  if(i<N){ int v = part[i] + bsum[i>>10]; row_ptr[i] = v; fill[i] = v; }
  else if(i==N){ row_ptr[N] = E; }
}

__global__ void fill_csr_kernel(const int* __restrict__ src, const int* __restrict__ dst,
                                int* __restrict__ fill, int* __restrict__ col, int E){
  int e = blockIdx.x*256 + threadIdx.x;
  if(e<E){
    int d = dst[e];
    int p = atomicAdd(&fill[d], 1);
    col[p] = src[e];
  }
}

// g[n, :] = dinv[n] * (h[n, :K] @ W[K,64]).  W transposed+padded into LDS so
// lane j reads its column with ds_read_b128 (2-way bank aliasing == free).
// 4 rows per wave per pass to amortize LDS traffic.
template<int K>
__global__ __launch_bounds__(256) void lin_kernel(const float* __restrict__ h,
                                                  const float* __restrict__ W,
                                                  const float* __restrict__ dinv,
                                                  float* __restrict__ g, int N){
  __shared__ __align__(16) float WT[64*(K+4)];
  int t = threadIdx.x;
  for(int idx=t; idx<K*64; idx+=256){
    int k = idx>>6, j = idx&63;          // W[k][j], row-major [K,64]
    WT[j*(K+4)+k] = W[idx];
  }
  __syncthreads();
  int wave = t>>6, lane = t&63;
  const float* wrow = &WT[lane*(K+4)];
  for(int base=(blockIdx.x*4+wave)*4; base<N; base+=gridDim.x*16){
    bool v1 = base+1<N, v2 = base+2<N, v3 = base+3<N;
    const float* h0 = &h[(size_t)base*K];
    const float* h1 = v1 ? &h[(size_t)(base+1)*K] : h0;
    const float* h2 = v2 ? &h[(size_t)(base+2)*K] : h0;
    const float* h3 = v3 ? &h[(size_t)(base+3)*K] : h0;
    float a0=0.f, a1=0.f, a2=0.f, a3=0.f;
    #pragma unroll 4
    for(int k=0; k<K; k+=4){
      float4 w4 = *(const float4*)&wrow[k];
      float4 x0 = *(const float4*)&h0[k];
      float4 x1 = *(const float4*)&h1[k];
      float4 x2 = *(const float4*)&h2[k];
      float4 x3 = *(const float4*)&h3[k];
      a0 += x0.x*w4.x + x0.y*w4.y + x0.z*w4.z + x0.w*w4.w;
      a1 += x1.x*w4.x + x1.y*w4.y + x1.z*w4.z + x1.w*w4.w;
      a2 += x2.x*w4.x + x2.y*w4.y + x2.z*w4.z + x2.w*w4.w;
      a3 += x3.x*w4.x + x3.y*w4.y + x3.z*w4.z + x3.w*w4.w;
    }
    g[(size_t)base*64+lane] = dinv[base]*a0;
    if(v1) g[(size_t)(base+1)*64+lane] = dinv[base+1]*a1;
    if(v2) g[(size_t)(base+2)*64+lane] = dinv[base+2]*a2;
    if(v3) g[(size_t)(base+3)*64+lane] = dinv[base+3]*a3;
  }
}

// h[n,:] = relu(dinv[n]*(g[n,:] + sum_{e in CSR[n]} g[col[e],:]) + bias).
// One wave per node; lane == feature. 256B coalesced row gathers.
__global__ __launch_bounds__(256) void agg_kernel(const float* __restrict__ g,
                                                  const int* __restrict__ row_ptr,
                                                  const int* __restrict__ col,
                                                  const float* __restrict__ dinv,
                                                  const float* __restrict__ bias,
                                                  float* __restrict__ h, int N){
  int wave = threadIdx.x>>6, lane = threadIdx.x&63;
  int n = blockIdx.x*4 + wave;
  if(n>=N) return;
  int s = row_ptr[n], e = row_ptr[n+1];
  float acc = g[(size_t)n*64 + lane];          // self loop
  int i = s;
  for(; i+4<=e; i+=4){
    int c0=col[i], c1=col[i+1], c2=col[i+2], c3=col[i+3];
    float x0 = g[(size_t)c0*64 + lane];
    float x1 = g[(size_t)c1*64 + lane];
    float x2 = g[(size_t)c2*64 + lane];
    float x3 = g[(size_t)c3*64 + lane];
    acc += (x0+x1) + (x2+x3);
  }
  for(; i<e; ++i) acc += g[(size_t)col[i]*64 + lane];
  float r = dinv[n]*acc + bias[lane];
  h[(size_t)n*64 + lane] = fmaxf(r, 0.0f);
}

// logits = h3 @ Wfc[64,2] + bfc; out = log_softmax over C=2.
__global__ __launch_bounds__(256) void final_kernel(const float* __restrict__ h,
                                                    const float* __restrict__ Wfc,
                                                    const float* __restrict__ bfc,
                                                    float* __restrict__ out, int N){
  int wave = threadIdx.x>>6, lane = threadIdx.x&63;
  int n = blockIdx.x*4 + wave;
  if(n>=N) return;
  float hv = h[(size_t)n*64 + lane];
  float2 w = *(const float2*)&Wfc[lane*2];     // Wfc row-major [64,2]
  float p0 = hv*w.x, p1 = hv*w.y;
  for(int off=32; off; off>>=1){
    p0 += __shfl_down(p0, off);
    p1 += __shfl_down(p1, off);
  }
  if(lane==0){
    float l0 = p0 + bfc[0], l1 = p1 + bfc[1];
    float m  = fmaxf(l0, l1);
    float lse = m + logf(expf(l0-m) + expf(l1-m));
    out[(size_t)n*2+0] = l0 - lse;
    out[(size_t)n*2+1] = l1 - lse;
  }
}

extern "C" void kernel_launch(void* const* d_in, const int* in_sizes, int n_in,
                              void* d_out, int out_size, void* d_ws, size_t ws_size,
                              hipStream_t stream) {
  (void)n_in; (void)out_size; (void)ws_size;
  const float* x   = (const float*)d_in[0];
  const int*   ei  = (const int*)  d_in[1];
  const float* W1  = (const float*)d_in[2];
  const float* b1  = (const float*)d_in[3];
  const float* W2  = (const float*)d_in[4];
  const float* b2  = (const float*)d_in[5];
  const float* W3  = (const float*)d_in[6];
  const float* b3  = (const float*)d_in[7];
  const float* Wfc = (const float*)d_in[8];
  const float* bfc = (const float*)d_in[9];
  float* out = (float*)d_out;

  const int N = in_sizes[0] / 128;   // 100000
  const int E = in_sizes[1] / 2;     // 1600000
  const int* src = ei;
  const int* dst = ei + E;

  // ---- workspace carve (all 512B aligned) ----
  char* w = (char*)d_ws;
  float* dinv    = (float*)w; w += alignup((size_t)N*4);
  int*   degi    = (int*)  w; w += alignup((size_t)N*4);
  int*   part    = (int*)  w; w += alignup((size_t)N*4);
  int*   row_ptr = (int*)  w; w += alignup((size_t)(N+1)*4);
  int*   fill    = (int*)  w; w += alignup((size_t)N*4);
  int*   bsum    = (int*)  w; w += alignup((size_t)1024*4);
  int*   col     = (int*)  w; w += alignup((size_t)E*4);
  float* bufA    = (float*)w; w += alignup((size_t)N*64*4);
  float* bufB    = (float*)w; w += alignup((size_t)N*64*4);

  const int nbScan = (N + 1023) / 1024;

  // ---- graph build ----
  zero_int_kernel<<<(N+255)/256, 256, 0, stream>>>(degi, N);
  count_deg_kernel<<<(E+255)/256, 256, 0, stream>>>(dst, degi, E);
  dinv_kernel<<<(N+255)/256, 256, 0, stream>>>(degi, dinv, N);
  scan_block_kernel<<<nbScan, 256, 0, stream>>>(degi, part, bsum, N);
  scan_bsum_kernel<<<1, 256, 0, stream>>>(bsum, nbScan);
  finalize_kernel<<<(N+1+255)/256, 256, 0, stream>>>(part, bsum, row_ptr, fill, N, E);
  fill_csr_kernel<<<(E+255)/256, 256, 0, stream>>>(src, dst, fill, col, E);

  // ---- layer 1: x[N,128] -> bufB ----
  lin_kernel<128><<<1024, 256, 0, stream>>>(x, W1, dinv, bufA, N);
  agg_kernel<<<(N+3)/4, 256, 0, stream>>>(bufA, row_ptr, col, dinv, b1, bufB, N);
  // ---- layer 2 ----
  lin_kernel<64><<<1024, 256, 0, stream>>>(bufB, W2, dinv, bufA, N);
  agg_kernel<<<(N+3)/4, 256, 0, stream>>>(bufA, row_ptr, col, dinv, b2, bufB, N);
  // ---- layer 3 ----
  lin_kernel<64><<<1024, 256, 0, stream>>>(bufB, W3, dinv, bufA, N);
  agg_kernel<<<(N+3)/4, 256, 0, stream>>>(bufA, row_ptr, col, dinv, b3, bufB, N);
  // ---- FC + log_softmax ----
  final_kernel<<<(N+3)/4, 256, 0, stream>>>(bufB, Wfc, bfc, out, N);
}

// Round 2
// 566.223 us; speedup vs baseline: 1.3154x; 1.3154x over previous
//
#include <hip/hip_runtime.h>
#include <math.h>

// ---------------------------------------------------------------------------
// FraudDetectionGCN: 3x GCNConv(relu) + FC + log_softmax, fp32 throughout.
// R2 changes vs R1:
//  * CSR build via 1024-bucket sort (hist -> scan -> chunked scatter of packed
//    (ldst<<17|src) -> per-bucket LDS counting sort). Kills the 16x write
//    amplification of the random col[] scatter (105 MB -> ~12 MB writes).
//  * lin layers read transposed W from global (L1-resident, coalesced float4)
//    instead of LDS (which had 8-way bank conflicts + 33KB occupancy cap).
//  * agg unrolled 8-wide for more memory-level parallelism.
// norm factorization: out[n] = dinv[n]*(sum_{s->n} g[s] + g[n]) + b,
// where g = dinv[:,None] * (h @ W).
// ---------------------------------------------------------------------------

static inline size_t alignup(size_t x){ return (x + 511) & ~size_t(511); }

#define NBUCK 1024          // histogram bins (dst>>7), NB=ceil(N/128) used
#define CHUNK 8192          // edges per block in hist/scatter
#define CCAP  3584          // max edges per bucket (mean ~2046, +30 sigma)

__global__ void zero_kernel(int* __restrict__ p, int n){
  int i = blockIdx.x*256 + threadIdx.x;
  if(i<n) p[i] = 0;
}

// WT[j*K + k] = W[k*64 + j] for all three layer weights (one launch).
__global__ void transpose_w_kernel(const float* __restrict__ W1, const float* __restrict__ W2,
                                   const float* __restrict__ W3, float* __restrict__ WT1,
                                   float* __restrict__ WT2, float* __restrict__ WT3){
  int i = blockIdx.x*256 + threadIdx.x;
  if(i < 128*64){ int k=i>>6, j=i&63; WT1[j*128+k] = W1[i]; }
  else if(i < 128*64+64*64){ int m=i-128*64; int k=m>>6, j=m&63; WT2[j*64+k]=W2[m]; }
  else if(i < 128*64+2*64*64){ int m=i-128*64-64*64; int k=m>>6, j=m&63; WT3[j*64+k]=W3[m]; }
}

// Pass A: global histogram of dst>>7 (LDS-aggregated).
__global__ __launch_bounds__(256) void hist_kernel(const int* __restrict__ dst,
                                                   int* __restrict__ bcnt, int E){
  __shared__ int h[NBUCK];
  int t = threadIdx.x;
  for(int i=t;i<NBUCK;i+=256) h[i]=0;
  __syncthreads();
  int base = blockIdx.x*CHUNK;
  #pragma unroll 4
  for(int i=0;i<CHUNK;i+=256){
    int e = base+i+t;
    if(e<E) atomicAdd(&h[dst[e]>>7], 1);
  }
  __syncthreads();
  for(int i=t;i<NBUCK;i+=256) if(h[i]) atomicAdd(&bcnt[i], h[i]);
}

// Exclusive scan of 1024 bucket counts (single block). bbase = bfill = prefix.
__global__ void scan_buckets_kernel(const int* __restrict__ bcnt, int* __restrict__ bbase,
                                    int* __restrict__ bfill){
  __shared__ int sh[256];
  int t = threadIdx.x;
  int v0=bcnt[4*t], v1=bcnt[4*t+1], v2=bcnt[4*t+2], v3=bcnt[4*t+3];
  int ts = v0+v1+v2+v3;
  sh[t]=ts; __syncthreads();
  for(int off=1; off<256; off<<=1){
    int x=(t>=off)?sh[t-off]:0; __syncthreads();
    sh[t]+=x; __syncthreads();
  }
  int run = sh[t]-ts;
  int i0=4*t;
  bbase[i0+0]=run; bfill[i0+0]=run; run+=v0;
  bbase[i0+1]=run; bfill[i0+1]=run; run+=v1;
  bbase[i0+2]=run; bfill[i0+2]=run; run+=v2;
  bbase[i0+3]=run; bfill[i0+3]=run;
}

// Pass B: scatter packed (local_dst<<17 | src) into bucket regions.
// Each block reserves per-bucket ranges with ONE global atomic per bucket,
// then fills them via LDS slot counters -> ~sequential writes per bucket.
__global__ __launch_bounds__(256) void scatter_kernel(const int* __restrict__ src,
                                                      const int* __restrict__ dst,
                                                      int* __restrict__ bfill,
                                                      int* __restrict__ pairs, int E){
  __shared__ int h[NBUCK];
  __shared__ int base[NBUCK];
  int t = threadIdx.x;
  for(int i=t;i<NBUCK;i+=256) h[i]=0;
  __syncthreads();
  int cbase = blockIdx.x*CHUNK;
  int d[CHUNK/256];
  #pragma unroll
  for(int i=0;i<CHUNK/256;i++){
    int e = cbase+i*256+t;
    d[i] = (e<E) ? dst[e] : -1;
    if(d[i]>=0) atomicAdd(&h[d[i]>>7], 1);
  }
  __syncthreads();
  for(int i=t;i<NBUCK;i+=256) base[i] = h[i] ? atomicAdd(&bfill[i], h[i]) : 0;
  __syncthreads();
  #pragma unroll
  for(int i=0;i<CHUNK/256;i++){
    int e = cbase+i*256+t;
    if(d[i]>=0){
      int b = d[i]>>7;
      int slot = atomicAdd(&base[b], 1);
      pairs[slot] = ((d[i]&127)<<17) | src[e];
    }
  }
}

// Pass C: one block per bucket (128 dst nodes). LDS counting sort ->
// row_ptr, dinv, and fully-sequential col writes.
__global__ __launch_bounds__(256) void bucket_csr_kernel(const int* __restrict__ pairs,
                                                         const int* __restrict__ bbase,
                                                         int* __restrict__ row_ptr,
                                                         float* __restrict__ dinv,
                                                         int* __restrict__ col,
                                                         int N, int E){
  __shared__ int hist[128];
  __shared__ int pref[128];
  __shared__ int fill[128];
  __shared__ int srcs[CCAP];
  int b = blockIdx.x, t = threadIdx.x;
  int s = bbase[b], e = bbase[b+1];
  int cnt = e - s; if(cnt > CCAP) cnt = CCAP;   // unreachable guard
  if(t<128) hist[t]=0;
  __syncthreads();
  int v[CCAP/256];
  #pragma unroll
  for(int i=0;i<CCAP/256;i++){
    int idx = i*256 + t;
    if(idx<cnt){ v[i]=pairs[s+idx]; atomicAdd(&hist[v[i]>>17], 1); }
  }
  __syncthreads();
  if(t<128) pref[t]=hist[t];
  __syncthreads();
  for(int off=1; off<128; off<<=1){
    int x=0;
    if(t<128 && t>=off) x=pref[t-off];
    __syncthreads();
    if(t<128) pref[t]+=x;
    __syncthreads();
  }
  if(t<128){
    int ex = pref[t]-hist[t];                 // exclusive prefix
    fill[t]=ex;
    int node = b*128 + t;
    if(node<N){
      row_ptr[node] = s + ex;
      dinv[node] = rsqrtf((float)(hist[t]+1)); // +1 self loop
    }
  }
  if(b==0 && t==0) row_ptr[N]=E;
  __syncthreads();
  #pragma unroll
  for(int i=0;i<CCAP/256;i++){
    int idx = i*256 + t;
    if(idx<cnt){
      int ld = v[i]>>17;
      int pos = atomicAdd(&fill[ld], 1);
      srcs[pos] = v[i] & 0x1FFFF;
    }
  }
  __syncthreads();
  for(int i=t;i<cnt;i+=256) col[s+i]=srcs[i];
}

// g[n,:] = dinv[n] * (h[n,:K] @ W[K,64]).  WT[j*K+k] read from global:
// lane j reads contiguous float4 of its column -> coalesced, L1-resident.
// h loads are lane-uniform (base made wave-uniform via readfirstlane).
template<int K>
__global__ __launch_bounds__(256) void lin_kernel(const float* __restrict__ h,
                                                  const float* __restrict__ WT,
                                                  const float* __restrict__ dinv,
                                                  float* __restrict__ g, int N){
  int t = threadIdx.x, wave = t>>6, lane = t&63;
  const float* wrow = &WT[lane*K];
  for(int base0=(blockIdx.x*4+wave)*4; base0<N; base0+=gridDim.x*16){
    int base = __builtin_amdgcn_readfirstlane(base0);
    bool v1 = base+1<N, v2 = base+2<N, v3 = base+3<N;
    const float* h0 = &h[(size_t)base*K];
    const float* h1 = v1 ? &h[(size_t)(base+1)*K] : h0;
    const float* h2 = v2 ? &h[(size_t)(base+2)*K] : h0;
    const float* h3 = v3 ? &h[(size_t)(base+3)*K] : h0;
    float a0=0.f, a1=0.f, a2=0.f, a3=0.f;
    #pragma unroll 4
    for(int k=0; k<K; k+=4){
      float4 w4 = *(const float4*)&wrow[k];
      float4 x0 = *(const float4*)&h0[k];
      float4 x1 = *(const float4*)&h1[k];
      float4 x2 = *(const float4*)&h2[k];
      float4 x3 = *(const float4*)&h3[k];
      a0 += x0.x*w4.x + x0.y*w4.y + x0.z*w4.z + x0.w*w4.w;
      a1 += x1.x*w4.x + x1.y*w4.y + x1.z*w4.z + x1.w*w4.w;
      a2 += x2.x*w4.x + x2.y*w4.y + x2.z*w4.z + x2.w*w4.w;
      a3 += x3.x*w4.x + x3.y*w4.y + x3.z*w4.z + x3.w*w4.w;
    }
    g[(size_t)base*64+lane] = dinv[base]*a0;
    if(v1) g[(size_t)(base+1)*64+lane] = dinv[base+1]*a1;
    if(v2) g[(size_t)(base+2)*64+lane] = dinv[base+2]*a2;
    if(v3) g[(size_t)(base+3)*64+lane] = dinv[base+3]*a3;
  }
}

// h[n,:] = relu(dinv[n]*(g[n,:] + sum_{CSR} g[col,:]) + bias). One wave/node,
// lane == feature; 8-deep unroll for outstanding 256B row gathers.
__global__ __launch_bounds__(256) void agg_kernel(const float* __restrict__ g,
                                                  const int* __restrict__ row_ptr,
                                                  const int* __restrict__ col,
                                                  const float* __restrict__ dinv,
                                                  const float* __restrict__ bias,
                                                  float* __restrict__ h, int N){
  int wave = threadIdx.x>>6, lane = threadIdx.x&63;
  int n = blockIdx.x*4 + wave;
  if(n>=N) return;
  int s = row_ptr[n], e = row_ptr[n+1];
  float acc = g[(size_t)n*64 + lane];          // self loop
  int i = s;
  for(; i+8<=e; i+=8){
    int c0=col[i],c1=col[i+1],c2=col[i+2],c3=col[i+3];
    int c4=col[i+4],c5=col[i+5],c6=col[i+6],c7=col[i+7];
    float x0=g[(size_t)c0*64+lane], x1=g[(size_t)c1*64+lane];
    float x2=g[(size_t)c2*64+lane], x3=g[(size_t)c3*64+lane];
    float x4=g[(size_t)c4*64+lane], x5=g[(size_t)c5*64+lane];
    float x6=g[(size_t)c6*64+lane], x7=g[(size_t)c7*64+lane];
    acc += ((x0+x1)+(x2+x3)) + ((x4+x5)+(x6+x7));
  }
  for(; i<e; ++i) acc += g[(size_t)col[i]*64 + lane];
  float r = dinv[n]*acc + bias[lane];
  h[(size_t)n*64 + lane] = fmaxf(r, 0.0f);
}

// logits = h3 @ Wfc[64,2] + bfc; out = log_softmax over C=2.
__global__ __launch_bounds__(256) void final_kernel(const float* __restrict__ h,
                                                    const float* __restrict__ Wfc,
                                                    const float* __restrict__ bfc,
                                                    float* __restrict__ out, int N){
  int wave = threadIdx.x>>6, lane = threadIdx.x&63;
  int n = blockIdx.x*4 + wave;
  if(n>=N) return;
  float hv = h[(size_t)n*64 + lane];
  float2 w = *(const float2*)&Wfc[lane*2];
  float p0 = hv*w.x, p1 = hv*w.y;
  for(int off=32; off; off>>=1){
    p0 += __shfl_down(p0, off);
    p1 += __shfl_down(p1, off);
  }
  if(lane==0){
    float l0 = p0 + bfc[0], l1 = p1 + bfc[1];
    float m  = fmaxf(l0, l1);
    float lse = m + logf(expf(l0-m) + expf(l1-m));
    out[(size_t)n*2+0] = l0 - lse;
    out[(size_t)n*2+1] = l1 - lse;
  }
}

extern "C" void kernel_launch(void* const* d_in, const int* in_sizes, int n_in,
                              void* d_out, int out_size, void* d_ws, size_t ws_size,
                              hipStream_t stream) {
  (void)n_in; (void)out_size; (void)ws_size;
  const float* x   = (const float*)d_in[0];
  const int*   ei  = (const int*)  d_in[1];
  const float* W1  = (const float*)d_in[2];
  const float* b1  = (const float*)d_in[3];
  const float* W2  = (const float*)d_in[4];
  const float* b2  = (const float*)d_in[5];
  const float* W3  = (const float*)d_in[6];
  const float* b3  = (const float*)d_in[7];
  const float* Wfc = (const float*)d_in[8];
  const float* bfc = (const float*)d_in[9];
  float* out = (float*)d_out;

  const int N = in_sizes[0] / 128;   // 100000
  const int E = in_sizes[1] / 2;     // 1600000
  const int* src = ei;
  const int* dst = ei + E;
  const int NB = (N + 127) / 128;    // 782 buckets

  // ---- workspace carve ----
  char* w = (char*)d_ws;
  float* WT1     = (float*)w; w += alignup((size_t)64*128*4);
  float* WT2     = (float*)w; w += alignup((size_t)64*64*4);
  float* WT3     = (float*)w; w += alignup((size_t)64*64*4);
  int*   bcnt    = (int*)  w; w += alignup((size_t)NBUCK*4);
  int*   bbase   = (int*)  w; w += alignup((size_t)(NBUCK+1)*4);
  int*   bfill   = (int*)  w; w += alignup((size_t)NBUCK*4);
  int*   pairs   = (int*)  w; w += alignup((size_t)E*4);
  int*   row_ptr = (int*)  w; w += alignup((size_t)(N+1)*4);
  float* dinv    = (float*)w; w += alignup((size_t)N*4);
  int*   col     = (int*)  w; w += alignup((size_t)E*4);
  float* bufA    = (float*)w; w += alignup((size_t)N*64*4);
  float* bufB    = (float*)w; w += alignup((size_t)N*64*4);

  const int nblkE = (E + CHUNK - 1) / CHUNK;   // 196

  // ---- CSR build ----
  zero_kernel<<<(NBUCK+255)/256, 256, 0, stream>>>(bcnt, NBUCK);
  transpose_w_kernel<<<64, 256, 0, stream>>>(W1, W2, W3, WT1, WT2, WT3);
  hist_kernel<<<nblkE, 256, 0, stream>>>(dst, bcnt, E);
  scan_buckets_kernel<<<1, 256, 0, stream>>>(bcnt, bbase, bfill);
  scatter_kernel<<<nblkE, 256, 0, stream>>>(src, dst, bfill, pairs, E);
  bucket_csr_kernel<<<NB, 256, 0, stream>>>(pairs, bbase, row_ptr, dinv, col, N, E);

  // ---- layer 1: x[N,128] ----
  lin_kernel<128><<<1024, 256, 0, stream>>>(x, WT1, dinv, bufA, N);
  agg_kernel<<<(N+3)/4, 256, 0, stream>>>(bufA, row_ptr, col, dinv, b1, bufB, N);
  // ---- layer 2 ----
  lin_kernel<64><<<1024, 256, 0, stream>>>(bufB, WT2, dinv, bufA, N);
  agg_kernel<<<(N+3)/4, 256, 0, stream>>>(bufA, row_ptr, col, dinv, b2, bufB, N);
  // ---- layer 3 ----
  lin_kernel<64><<<1024, 256, 0, stream>>>(bufB, WT3, dinv, bufA, N);
  agg_kernel<<<(N+3)/4, 256, 0, stream>>>(bufA, row_ptr, col, dinv, b3, bufB, N);
  // ---- FC + log_softmax ----
  final_kernel<<<(N+3)/4, 256, 0, stream>>>(bufB, Wfc, bfc, out, N);
}